// Round 1
// baseline (4872.643 us; speedup 1.0000x reference)
//
#include <hip/hip_runtime.h>
#include <stdint.h>

#define BB 64
#define TT 128
#define INF 257
#define KP 288
#define HH 1024
#define G4 4096

typedef _Float16 half8 __attribute__((ext_vector_type(8)));
typedef float f4 __attribute__((ext_vector_type(4)));

__device__ __forceinline__ f4 mfma16(half8 a, half8 b, f4 c) {
  return __builtin_amdgcn_mfma_f32_16x16x32_f16(a, b, c, 0, 0, 0);
}

// async global->LDS, 16B per lane; l must be wave-uniform base, lanes land at l + lane*16
__device__ __forceinline__ void gld_lds16(const void* g, void* l) {
  auto gp = reinterpret_cast<__attribute__((address_space(1))) void*>(reinterpret_cast<uintptr_t>(g));
  auto lp = reinterpret_cast<__attribute__((address_space(3))) void*>(reinterpret_cast<uintptr_t>(l));
  __builtin_amdgcn_global_load_lds(gp, lp, 16, 0, 0);
}

// ---------- prep kernels ----------
__global__ __launch_bounds__(256) void k_cast_X(const float* __restrict__ X, _Float16* __restrict__ Xt) {
  int o = blockIdx.x * 256 + threadIdx.x;
  if (o >= TT * BB * KP) return;
  int k = o % KP, m = o / KP;
  int t = m >> 6, b = m & 63;
  float v = (k < INF) ? X[((size_t)b * TT + t) * INF + k] : 0.f;
  Xt[o] = (_Float16)v;
}

__global__ __launch_bounds__(256) void k_cast_padW(const float* __restrict__ W, _Float16* __restrict__ Wp) {
  int o = blockIdx.x * 256 + threadIdx.x;
  if (o >= G4 * KP) return;
  int k = o % KP, n = o / KP;
  Wp[o] = (_Float16)((k < INF) ? W[(size_t)n * INF + k] : 0.f);
}

__global__ __launch_bounds__(256) void k_cast(const float* __restrict__ W, _Float16* __restrict__ Wh, int n) {
  int o = blockIdx.x * 256 + threadIdx.x;
  if (o < n) Wh[o] = (_Float16)W[o];
}

__global__ __launch_bounds__(256) void k_bias(const float* __restrict__ a, const float* __restrict__ b,
                                              const float* __restrict__ c, const float* __restrict__ d,
                                              float* __restrict__ b0, float* __restrict__ b1) {
  int o = blockIdx.x * 256 + threadIdx.x;
  if (o < G4) { b0[o] = a[o] + b[o]; b1[o] = c[o] + d[o]; }
}

// ---------- big GEMM: C[M,4096] = A[M,K] @ Bw[N,K]^T + bias, fp16 out ----------
// 128x128 tile, 4 waves in 2x2 quadrants of 64x64, 16x16x32 fp16 MFMA.
// LDS layout [kc(4)][row(128)][8 halves] so frag b128 reads are 2-way (free) bank aliased.
__global__ __launch_bounds__(256) void k_gemm(const _Float16* __restrict__ A, const _Float16* __restrict__ Bw,
                                              const float* __restrict__ bias, _Float16* __restrict__ C,
                                              int K, int lda, int ldb) {
  __shared__ __align__(16) _Float16 As[4 * 128 * 8];
  __shared__ __align__(16) _Float16 Bs[4 * 128 * 8];
  const int tid = threadIdx.x;
  const int w = tid >> 6, lane = tid & 63;
  const int q = lane >> 4, ml = lane & 15;
  const int m0 = blockIdx.x * 128, n0 = blockIdx.y * 128;
  const int wm = (w >> 1) * 64, wn = (w & 1) * 64;
  f4 acc[4][4] = {};
  const int kt_iters = K >> 5;
  for (int kt = 0; kt < kt_iters; ++kt) {
    __syncthreads();
#pragma unroll
    for (int i = 0; i < 2; ++i) {
      int cb = i * 256 + w * 64;          // wave-uniform base chunk
      int kc = cb >> 7, mb = cb & 127;    // chunk -> [kc][row] map
      gld_lds16(A + (size_t)(m0 + mb + lane) * lda + kt * 32 + kc * 8, (char*)As + (size_t)cb * 16);
      gld_lds16(Bw + (size_t)(n0 + mb + lane) * ldb + kt * 32 + kc * 8, (char*)Bs + (size_t)cb * 16);
    }
    __syncthreads();
    half8 af[4], bf[4];
#pragma unroll
    for (int tm = 0; tm < 4; ++tm) af[tm] = *(const half8*)(As + ((size_t)q * 128 + wm + tm * 16 + ml) * 8);
#pragma unroll
    for (int tn = 0; tn < 4; ++tn) bf[tn] = *(const half8*)(Bs + ((size_t)q * 128 + wn + tn * 16 + ml) * 8);
#pragma unroll
    for (int tm = 0; tm < 4; ++tm)
#pragma unroll
      for (int tn = 0; tn < 4; ++tn)
        acc[tm][tn] = mfma16(af[tm], bf[tn], acc[tm][tn]);
  }
#pragma unroll
  for (int tn = 0; tn < 4; ++tn) {
    int n = n0 + wn + tn * 16 + ml;
    float bv = bias[n];
#pragma unroll
    for (int tm = 0; tm < 4; ++tm) {
#pragma unroll
      for (int r = 0; r < 4; ++r) {
        int m = m0 + wm + tm * 16 + q * 4 + r;   // C/D: row = quad*4+reg, col = lane&15
        C[(size_t)m * G4 + n] = (_Float16)(acc[tm][tn][r] + bv);
      }
    }
  }
}

// ---------- fused LSTM step: gates = xg + h_prev @ Whh^T, then activations + state update ----------
// grid 64 WGs (16 units each), 4 waves = 4 gates (i,f,g,o), full batch M=64 per wave.
// A (h_prev, 128KB) double-buffered 32-k slices through LDS; B (Whh slice) streamed from L2.
__global__ __launch_bounds__(256) void k_step(const _Float16* __restrict__ xg,    // [64][4096] at t
                                              const _Float16* __restrict__ hprev, // [64][1024] (t>0)
                                              const _Float16* __restrict__ Whh,   // [4096][1024]
                                              float* __restrict__ cst,            // [64][1024]
                                              _Float16* __restrict__ hout,        // [64][1024]
                                              int t) {
  __shared__ __align__(16) _Float16 As[2][4 * 64 * 8];  // [buf][kc][m][8]
  __shared__ float gl[4][64][16];                       // [gate][batch][unit]
  const int tid = threadIdx.x;
  const int w = tid >> 6, lane = tid & 63;
  const int q = lane >> 4, ml = lane & 15;
  const int u0 = blockIdx.x * 16;
  f4 acc[4] = {};
  if (t > 0) {
    // prologue: wave w stages kc=w slice of kt=0
    gld_lds16(hprev + (size_t)lane * HH + w * 8, (char*)As[0] + w * 1024);
    for (int kt = 0; kt < 32; ++kt) {
      int buf = kt & 1;
      __syncthreads();  // drains vmcnt: staged buf ready; previous readers of buf^1 done
      if (kt + 1 < 32)
        gld_lds16(hprev + (size_t)lane * HH + (kt + 1) * 32 + w * 8, (char*)As[buf ^ 1] + w * 1024);
      const _Float16* Ab = As[buf];
      half8 bfrag = *(const half8*)(Whh + (size_t)(w * HH + u0 + ml) * HH + kt * 32 + q * 8);
#pragma unroll
      for (int tm = 0; tm < 4; ++tm) {
        half8 af = *(const half8*)(Ab + ((size_t)q * 64 + tm * 16 + ml) * 8);
        acc[tm] = mfma16(af, bfrag, acc[tm]);
      }
    }
  }
  // cross-wave gate transport: C/D layout -> [gate][b][u]
#pragma unroll
  for (int tm = 0; tm < 4; ++tm)
#pragma unroll
    for (int r = 0; r < 4; ++r)
      gl[w][tm * 16 + q * 4 + r][ml] = acc[tm][r];
  __syncthreads();
  const int u = tid & 15, bb = (tid >> 4) * 4;
#pragma unroll
  for (int i = 0; i < 4; ++i) {
    int b = bb + i;
    int col = u0 + u;
    float gi = (float)xg[(size_t)b * G4 + col] + gl[0][b][u];
    float gf = (float)xg[(size_t)b * G4 + HH + col] + gl[1][b][u];
    float gg = (float)xg[(size_t)b * G4 + 2 * HH + col] + gl[2][b][u];
    float go = (float)xg[(size_t)b * G4 + 3 * HH + col] + gl[3][b][u];
    float I = 1.f / (1.f + __expf(-gi));
    float F = 1.f / (1.f + __expf(-gf));
    float G = tanhf(gg);
    float O = 1.f / (1.f + __expf(-go));
    float cp = (t > 0) ? cst[(size_t)b * HH + col] : 0.f;
    float cn = F * cp + I * G;
    cst[(size_t)b * HH + col] = cn;
    hout[(size_t)b * HH + col] = (_Float16)(O * tanhf(cn));
  }
}

// ---------- output head: out[b,t,j] = tanh(y2[t,b,:]) . Wy[j,:] + by[j] ----------
__global__ __launch_bounds__(256) void k_out(const _Float16* __restrict__ y2, const float* __restrict__ Wy,
                                             const float* __restrict__ by, float* __restrict__ out) {
  int gw = blockIdx.x * 4 + (threadIdx.x >> 6);
  int lane = threadIdx.x & 63;
  int t = gw >> 6, b = gw & 63;
  const _Float16* row = y2 + (size_t)gw * HH;
  float p0 = 0.f, p1 = 0.f;
#pragma unroll
  for (int i = 0; i < 16; ++i) {
    int k = i * 64 + lane;
    float v = tanhf((float)row[k]);
    p0 += v * Wy[k];
    p1 += v * Wy[HH + k];
  }
  for (int off = 32; off > 0; off >>= 1) {
    p0 += __shfl_down(p0, off);
    p1 += __shfl_down(p1, off);
  }
  if (lane == 0) {
    out[((size_t)b * TT + t) * 2 + 0] = p0 + by[0];
    out[((size_t)b * TT + t) * 2 + 1] = p1 + by[1];
  }
}

extern "C" void kernel_launch(void* const* d_in, const int* in_sizes, int n_in,
                              void* d_out, int out_size, void* d_ws, size_t ws_size,
                              hipStream_t stream) {
  (void)in_sizes; (void)n_in; (void)out_size; (void)ws_size;
  const float* X    = (const float*)d_in[0];
  const float* Wih0 = (const float*)d_in[3];
  const float* Whh0 = (const float*)d_in[4];
  const float* bih0 = (const float*)d_in[5];
  const float* bhh0 = (const float*)d_in[6];
  const float* Wih1 = (const float*)d_in[7];
  const float* Whh1 = (const float*)d_in[8];
  const float* bih1 = (const float*)d_in[9];
  const float* bhh1 = (const float*)d_in[10];
  const float* Wy   = (const float*)d_in[11];
  const float* by   = (const float*)d_in[12];
  float* out = (float*)d_out;

  char* p = (char*)d_ws;
  auto carve = [&](size_t bytes) { char* r = p; p += (bytes + 255) & ~(size_t)255; return r; };
  _Float16* Xt    = (_Float16*)carve((size_t)TT * BB * KP * 2);
  _Float16* W0p   = (_Float16*)carve((size_t)G4 * KP * 2);
  _Float16* Whh0h = (_Float16*)carve((size_t)G4 * HH * 2);
  _Float16* Wih1h = (_Float16*)carve((size_t)G4 * HH * 2);
  _Float16* Whh1h = (_Float16*)carve((size_t)G4 * HH * 2);
  float* b0 = (float*)carve((size_t)G4 * 4);
  float* b1 = (float*)carve((size_t)G4 * 4);
  _Float16* xg = (_Float16*)carve((size_t)TT * BB * G4 * 2);  // reused for both layers
  _Float16* y1 = (_Float16*)carve((size_t)TT * BB * HH * 2);
  _Float16* y2 = (_Float16*)carve((size_t)TT * BB * HH * 2);
  float* cst = (float*)carve((size_t)BB * HH * 4);

  k_cast_X<<<(TT * BB * KP + 255) / 256, 256, 0, stream>>>(X, Xt);
  k_cast_padW<<<(G4 * KP + 255) / 256, 256, 0, stream>>>(Wih0, W0p);
  k_cast<<<(G4 * HH + 255) / 256, 256, 0, stream>>>(Whh0, Whh0h, G4 * HH);
  k_cast<<<(G4 * HH + 255) / 256, 256, 0, stream>>>(Wih1, Wih1h, G4 * HH);
  k_cast<<<(G4 * HH + 255) / 256, 256, 0, stream>>>(Whh1, Whh1h, G4 * HH);
  k_bias<<<(G4 + 255) / 256, 256, 0, stream>>>(bih0, bhh0, bih1, bhh1, b0, b1);

  // layer 0: input projection then recurrence
  k_gemm<<<dim3(TT * BB / 128, G4 / 128), 256, 0, stream>>>(Xt, W0p, b0, xg, KP, KP, KP);
  for (int t = 0; t < TT; ++t)
    k_step<<<HH / 16, 256, 0, stream>>>(xg + (size_t)t * BB * G4,
                                        t ? y1 + (size_t)(t - 1) * BB * HH : (const _Float16*)nullptr,
                                        Whh0h, cst, y1 + (size_t)t * BB * HH, t);
  // layer 1
  k_gemm<<<dim3(TT * BB / 128, G4 / 128), 256, 0, stream>>>(y1, Wih1h, b1, xg, HH, HH, HH);
  for (int t = 0; t < TT; ++t)
    k_step<<<HH / 16, 256, 0, stream>>>(xg + (size_t)t * BB * G4,
                                        t ? y2 + (size_t)(t - 1) * BB * HH : (const _Float16*)nullptr,
                                        Whh1h, cst, y2 + (size_t)t * BB * HH, t);

  k_out<<<(TT * BB) / 4, 256, 0, stream>>>(y2, Wy, by, out);
}

// Round 2
// 2286.569 us; speedup vs baseline: 2.1310x; 2.1310x over previous
//
#include <hip/hip_runtime.h>
#include <stdint.h>

#define BB 64
#define TT 128
#define INF 257
#define KP 288
#define HH 1024
#define G4 4096

typedef _Float16 half8 __attribute__((ext_vector_type(8)));
typedef float f4 __attribute__((ext_vector_type(4)));

__device__ __forceinline__ f4 mfma16(half8 a, half8 b, f4 c) {
  return __builtin_amdgcn_mfma_f32_16x16x32_f16(a, b, c, 0, 0, 0);
}

// async global->LDS, 16B per lane; LDS dest is wave-uniform base + lane*16
__device__ __forceinline__ void gld_lds16(const void* g, void* l) {
  auto gp = reinterpret_cast<__attribute__((address_space(1))) void*>(reinterpret_cast<uintptr_t>(g));
  auto lp = reinterpret_cast<__attribute__((address_space(3))) void*>(reinterpret_cast<uintptr_t>(l));
  __builtin_amdgcn_global_load_lds(gp, lp, 16, 0, 0);
}

// ---------- prep kernels ----------
__global__ __launch_bounds__(256) void k_cast_X(const float* __restrict__ X, _Float16* __restrict__ Xt) {
  int o = blockIdx.x * 256 + threadIdx.x;
  if (o >= TT * BB * KP) return;
  int k = o % KP, m = o / KP;
  int t = m >> 6, b = m & 63;
  float v = (k < INF) ? X[((size_t)b * TT + t) * INF + k] : 0.f;
  Xt[o] = (_Float16)v;
}

__global__ __launch_bounds__(256) void k_cast_padW(const float* __restrict__ W, _Float16* __restrict__ Wp) {
  int o = blockIdx.x * 256 + threadIdx.x;
  if (o >= G4 * KP) return;
  int k = o % KP, n = o / KP;
  Wp[o] = (_Float16)((k < INF) ? W[(size_t)n * INF + k] : 0.f);
}

__global__ __launch_bounds__(256) void k_cast(const float* __restrict__ W, _Float16* __restrict__ Wh, int n) {
  int o = blockIdx.x * 256 + threadIdx.x;
  if (o < n) Wh[o] = (_Float16)W[o];
}

__global__ __launch_bounds__(256) void k_bias(const float* __restrict__ a, const float* __restrict__ b,
                                              const float* __restrict__ c, const float* __restrict__ d,
                                              float* __restrict__ b0, float* __restrict__ b1) {
  int o = blockIdx.x * 256 + threadIdx.x;
  if (o < G4) { b0[o] = a[o] + b[o]; b1[o] = c[o] + d[o]; }
}

// ---------- big GEMM: C[M,4096] = A[M,K] @ Bw[N,K]^T + bias, fp16 out ----------
__global__ __launch_bounds__(256) void k_gemm(const _Float16* __restrict__ A, const _Float16* __restrict__ Bw,
                                              const float* __restrict__ bias, _Float16* __restrict__ C,
                                              int K, int lda, int ldb) {
  __shared__ __align__(16) _Float16 As[4 * 128 * 8];
  __shared__ __align__(16) _Float16 Bs[4 * 128 * 8];
  const int tid = threadIdx.x;
  const int w = tid >> 6, lane = tid & 63;
  const int q = lane >> 4, ml = lane & 15;
  const int m0 = blockIdx.x * 128, n0 = blockIdx.y * 128;
  const int wm = (w >> 1) * 64, wn = (w & 1) * 64;
  f4 acc[4][4] = {};
  const int kt_iters = K >> 5;
  for (int kt = 0; kt < kt_iters; ++kt) {
    __syncthreads();
#pragma unroll
    for (int i = 0; i < 2; ++i) {
      int cb = i * 256 + w * 64;
      int kc = cb >> 7, mb = cb & 127;
      gld_lds16(A + (size_t)(m0 + mb + lane) * lda + kt * 32 + kc * 8, (char*)As + (size_t)cb * 16);
      gld_lds16(Bw + (size_t)(n0 + mb + lane) * ldb + kt * 32 + kc * 8, (char*)Bs + (size_t)cb * 16);
    }
    __syncthreads();
    half8 af[4], bf[4];
#pragma unroll
    for (int tm = 0; tm < 4; ++tm) af[tm] = *(const half8*)(As + ((size_t)q * 128 + wm + tm * 16 + ml) * 8);
#pragma unroll
    for (int tn = 0; tn < 4; ++tn) bf[tn] = *(const half8*)(Bs + ((size_t)q * 128 + wn + tn * 16 + ml) * 8);
#pragma unroll
    for (int tm = 0; tm < 4; ++tm)
#pragma unroll
      for (int tn = 0; tn < 4; ++tn)
        acc[tm][tn] = mfma16(af[tm], bf[tn], acc[tm][tn]);
  }
#pragma unroll
  for (int tn = 0; tn < 4; ++tn) {
    int n = n0 + wn + tn * 16 + ml;
    float bv = bias[n];
#pragma unroll
    for (int tm = 0; tm < 4; ++tm) {
#pragma unroll
      for (int r = 0; r < 4; ++r) {
        int m = m0 + wm + tm * 16 + q * 4 + r;
        C[(size_t)m * G4 + n] = (_Float16)(acc[tm][tn][r] + bv);
      }
    }
  }
}

// ---------- fused LSTM step (v2): 256 WGs, B register-resident, 2 barriers ----------
// WG (mg,ug): batch rows [mg*16,mg*16+16), units [ug*16,ug*16+16) across all 4 gates.
// Wave w handles K-quarter [w*256, w*256+256); per wave M=16 x N=64 (4 gate-tiles).
// B: 32 x dwordx4 -> 128 VGPRs, loaded once at start (L2-hot across launches).
// A: h rows staged once to LDS (32 KB) via global_load_lds.
__global__ __launch_bounds__(256) void k_step(const _Float16* __restrict__ xg,    // [64][4096] at t
                                              const _Float16* __restrict__ hprev, // [64][1024] (t>0)
                                              const _Float16* __restrict__ Whh,   // [4096][1024]
                                              float* __restrict__ cst,            // [64][1024]
                                              _Float16* __restrict__ hout,        // [64][1024]
                                              int t) {
  __shared__ __align__(16) _Float16 As[128 * 16 * 8];   // [k8][row][8] = 32 KB
  __shared__ float gl[4][4][16][16];                    // [kwave][gate][brow][unit] = 16 KB
  const int tid = threadIdx.x;
  const int w = tid >> 6, lane = tid & 63;
  const int q = lane >> 4, ml = lane & 15;
  const int ug = blockIdx.x & 63, mg = blockIdx.x >> 6;
  const int u0 = ug * 16, b0 = mg * 16;

  // epilogue-mapped prefetches (issue early, consumed after barrier 2)
  const int brow = tid >> 4, u = tid & 15;
  const int bi = b0 + brow, col = u0 + u;
  _Float16 xv0 = xg[(size_t)bi * G4 + 0 * HH + col];
  _Float16 xv1 = xg[(size_t)bi * G4 + 1 * HH + col];
  _Float16 xv2 = xg[(size_t)bi * G4 + 2 * HH + col];
  _Float16 xv3 = xg[(size_t)bi * G4 + 3 * HH + col];
  float cp0 = cst[(size_t)bi * HH + col];  // poison at t==0, selected away

  half8 bf[4][8];
  if (t > 0) {
    // B frags: col = tn*HH + u0 + ml (row of Whh), k = w*256 + kt*32 + q*8
    const _Float16* Bbase = Whh + (size_t)(u0 + ml) * HH + w * 256 + q * 8;
#pragma unroll
    for (int tn = 0; tn < 4; ++tn)
#pragma unroll
      for (int kt = 0; kt < 8; ++kt)
        bf[tn][kt] = *(const half8*)(Bbase + (size_t)tn * HH * HH + kt * 32);
    // A staging: chunk ci+lane -> As + (ci+lane)*16B; row=ml, k8=ci/16+q
#pragma unroll
    for (int j = 0; j < 8; ++j) {
      int ci = (w * 8 + j) * 64;
      gld_lds16(hprev + (size_t)(b0 + ml) * HH + (size_t)(ci / 16 + q) * 8,
                (char*)As + (size_t)ci * 16);
    }
  }
  __syncthreads();  // drains vmcnt: As staged, bf/xv/cp0 in regs

  f4 acc[4] = {};
  if (t > 0) {
#pragma unroll
    for (int kt = 0; kt < 8; ++kt) {
      half8 af = *(const half8*)(As + ((size_t)(w * 32 + kt * 4 + q) * 16 + ml) * 8);
#pragma unroll
      for (int tn = 0; tn < 4; ++tn)
        acc[tn] = mfma16(af, bf[tn][kt], acc[tn]);
    }
  }
  // K-partials to LDS; C/D layout: unit = ml, brow = q*4 + r
#pragma unroll
  for (int tn = 0; tn < 4; ++tn)
#pragma unroll
    for (int r = 0; r < 4; ++r)
      gl[w][tn][q * 4 + r][ml] = acc[tn][r];
  __syncthreads();

  // epilogue: one thread per (brow, u)
  float g0 = (float)xv0 + gl[0][0][brow][u] + gl[1][0][brow][u] + gl[2][0][brow][u] + gl[3][0][brow][u];
  float g1 = (float)xv1 + gl[0][1][brow][u] + gl[1][1][brow][u] + gl[2][1][brow][u] + gl[3][1][brow][u];
  float g2 = (float)xv2 + gl[0][2][brow][u] + gl[1][2][brow][u] + gl[2][2][brow][u] + gl[3][2][brow][u];
  float g3 = (float)xv3 + gl[0][3][brow][u] + gl[1][3][brow][u] + gl[2][3][brow][u] + gl[3][3][brow][u];
  float I = 1.f / (1.f + __expf(-g0));
  float F = 1.f / (1.f + __expf(-g1));
  float G = tanhf(g2);
  float O = 1.f / (1.f + __expf(-g3));
  float cp = (t > 0) ? cp0 : 0.f;
  float cn = F * cp + I * G;
  cst[(size_t)bi * HH + col] = cn;
  hout[(size_t)bi * HH + col] = (_Float16)(O * tanhf(cn));
}

// ---------- output head ----------
__global__ __launch_bounds__(256) void k_out(const _Float16* __restrict__ y2, const float* __restrict__ Wy,
                                             const float* __restrict__ by, float* __restrict__ out) {
  int gw = blockIdx.x * 4 + (threadIdx.x >> 6);
  int lane = threadIdx.x & 63;
  int t = gw >> 6, b = gw & 63;
  const _Float16* row = y2 + (size_t)gw * HH;
  float p0 = 0.f, p1 = 0.f;
#pragma unroll
  for (int i = 0; i < 16; ++i) {
    int k = i * 64 + lane;
    float v = tanhf((float)row[k]);
    p0 += v * Wy[k];
    p1 += v * Wy[HH + k];
  }
  for (int off = 32; off > 0; off >>= 1) {
    p0 += __shfl_down(p0, off);
    p1 += __shfl_down(p1, off);
  }
  if (lane == 0) {
    out[((size_t)b * TT + t) * 2 + 0] = p0 + by[0];
    out[((size_t)b * TT + t) * 2 + 1] = p1 + by[1];
  }
}

extern "C" void kernel_launch(void* const* d_in, const int* in_sizes, int n_in,
                              void* d_out, int out_size, void* d_ws, size_t ws_size,
                              hipStream_t stream) {
  (void)in_sizes; (void)n_in; (void)out_size; (void)ws_size;
  const float* X    = (const float*)d_in[0];
  const float* Wih0 = (const float*)d_in[3];
  const float* Whh0 = (const float*)d_in[4];
  const float* bih0 = (const float*)d_in[5];
  const float* bhh0 = (const float*)d_in[6];
  const float* Wih1 = (const float*)d_in[7];
  const float* Whh1 = (const float*)d_in[8];
  const float* bih1 = (const float*)d_in[9];
  const float* bhh1 = (const float*)d_in[10];
  const float* Wy   = (const float*)d_in[11];
  const float* by   = (const float*)d_in[12];
  float* out = (float*)d_out;

  char* p = (char*)d_ws;
  auto carve = [&](size_t bytes) { char* r = p; p += (bytes + 255) & ~(size_t)255; return r; };
  _Float16* Xt    = (_Float16*)carve((size_t)TT * BB * KP * 2);
  _Float16* W0p   = (_Float16*)carve((size_t)G4 * KP * 2);
  _Float16* Whh0h = (_Float16*)carve((size_t)G4 * HH * 2);
  _Float16* Wih1h = (_Float16*)carve((size_t)G4 * HH * 2);
  _Float16* Whh1h = (_Float16*)carve((size_t)G4 * HH * 2);
  float* b0 = (float*)carve((size_t)G4 * 4);
  float* b1 = (float*)carve((size_t)G4 * 4);
  _Float16* xg = (_Float16*)carve((size_t)TT * BB * G4 * 2);
  _Float16* y1 = (_Float16*)carve((size_t)TT * BB * HH * 2);
  _Float16* y2 = (_Float16*)carve((size_t)TT * BB * HH * 2);
  float* cst = (float*)carve((size_t)BB * HH * 4);

  k_cast_X<<<(TT * BB * KP + 255) / 256, 256, 0, stream>>>(X, Xt);
  k_cast_padW<<<(G4 * KP + 255) / 256, 256, 0, stream>>>(Wih0, W0p);
  k_cast<<<(G4 * HH + 255) / 256, 256, 0, stream>>>(Whh0, Whh0h, G4 * HH);
  k_cast<<<(G4 * HH + 255) / 256, 256, 0, stream>>>(Wih1, Wih1h, G4 * HH);
  k_cast<<<(G4 * HH + 255) / 256, 256, 0, stream>>>(Whh1, Whh1h, G4 * HH);
  k_bias<<<(G4 + 255) / 256, 256, 0, stream>>>(bih0, bhh0, bih1, bhh1, b0, b1);

  // layer 0
  k_gemm<<<dim3(TT * BB / 128, G4 / 128), 256, 0, stream>>>(Xt, W0p, b0, xg, KP, KP, KP);
  for (int t = 0; t < TT; ++t)
    k_step<<<256, 256, 0, stream>>>(xg + (size_t)t * BB * G4,
                                    t ? y1 + (size_t)(t - 1) * BB * HH : (const _Float16*)nullptr,
                                    Whh0h, cst, y1 + (size_t)t * BB * HH, t);
  // layer 1
  k_gemm<<<dim3(TT * BB / 128, G4 / 128), 256, 0, stream>>>(y1, Wih1h, b1, xg, HH, HH, HH);
  for (int t = 0; t < TT; ++t)
    k_step<<<256, 256, 0, stream>>>(xg + (size_t)t * BB * G4,
                                    t ? y2 + (size_t)(t - 1) * BB * HH : (const _Float16*)nullptr,
                                    Whh1h, cst, y2 + (size_t)t * BB * HH, t);

  k_out<<<(TT * BB) / 4, 256, 0, stream>>>(y2, Wy, by, out);
}